// Round 6
// baseline (250.841 us; speedup 1.0000x reference)
//
#include <hip/hip_runtime.h>
#include <hip/hip_bf16.h>
#include <cstdint>

#define TOKENS 8192
#define DIN 1024
#define DOUT 1024
#define NE 8

typedef __bf16 bf16;
typedef __attribute__((ext_vector_type(8))) __bf16 bf16x8;
typedef __attribute__((ext_vector_type(4))) float floatx4;
typedef __attribute__((ext_vector_type(2))) float floatx2;

// async global->LDS, 16B per lane. LDS dest must be wave-uniform base + lane*16.
__device__ __forceinline__ void async16(const void* gptr, void* lptr) {
  __builtin_amdgcn_global_load_lds(
      (const __attribute__((address_space(1))) void*)gptr,
      (__attribute__((address_space(3))) void*)lptr,
      16, 0, 0);
}

// ---------------------------------------------------------------------------
// Gate (unchanged from R11): gate softmax + x -> bf16 FRAGMENT-MAJOR layout
// xbf[tg][kt][kk][lq][tok16][8] so moe_gemm's A-frag loads are lane-contiguous
// 1KB dwordx4.
// ---------------------------------------------------------------------------
__global__ __launch_bounds__(256) void gate_kernel(
    const float* __restrict__ x, const float* __restrict__ gw,
    const float* __restrict__ gb, float* __restrict__ g,
    bf16* __restrict__ xbf) {
  __shared__ __align__(16) float gws[NE * DIN];   // 32 KB, gw transposed
  __shared__ __align__(16) bf16 xtile[8][1032];   // 16.5 KB (pad 8 elems)

  const int tid = threadIdx.x;
  const int bg = blockIdx.x;
#pragma unroll
  for (int k = 0; k < 8; ++k) {
    const int base = (k * 256 + tid) * 4;
    const floatx4 v = *(const floatx4*)(gw + base);
#pragma unroll
    for (int m = 0; m < 4; ++m) {
      const int j = base + m;
      gws[(j & 7) * DIN + (j >> 3)] = v[m];
    }
  }
  __syncthreads();

  const int lane = tid & 63;
  const int wave = tid >> 6;

#pragma unroll
  for (int h = 0; h < 2; ++h) {
#pragma unroll
    for (int tt = 0; tt < 2; ++tt) {
      const int tl = h * 8 + tt * 4 + wave;   // token-in-group 0..15
      const int t = bg * 16 + tl;
      const float* xr = x + (size_t)t * DIN;
      bf16* const xrow = &xtile[tl & 7][0];

      float acc[NE];
#pragma unroll
      for (int e = 0; e < NE; ++e) acc[e] = 0.f;

#pragma unroll
      for (int it = 0; it < 4; ++it) {
        const int i = it * 256 + lane * 4;
        const floatx4 xv = *(const floatx4*)(xr + i);
        union { bf16 b[4]; uint64_t u; } cv;
#pragma unroll
        for (int m = 0; m < 4; ++m) cv.b[m] = (bf16)xv[m];
        *(uint64_t*)(xrow + i) = cv.u;
#pragma unroll
        for (int e = 0; e < NE; ++e) {
          const floatx4 wv = *(const floatx4*)(gws + e * DIN + i);
          acc[e] += xv[0] * wv[0] + xv[1] * wv[1] + xv[2] * wv[2] + xv[3] * wv[3];
        }
      }
#pragma unroll
      for (int e = 0; e < NE; ++e)
#pragma unroll
        for (int off = 32; off > 0; off >>= 1)
          acc[e] += __shfl_xor(acc[e], off, 64);

      float lg[NE];
      float mx = -3.0e38f;
#pragma unroll
      for (int e = 0; e < NE; ++e) { lg[e] = acc[e] + gb[e]; mx = fmaxf(mx, lg[e]); }
      float s = 0.f;
#pragma unroll
      for (int e = 0; e < NE; ++e) { lg[e] = __expf(lg[e] - mx); s += lg[e]; }
      const float inv = 1.f / s;
      if (lane == 0) {
        floatx4 o0, o1;
#pragma unroll
        for (int e = 0; e < 4; ++e) { o0[e] = lg[e] * inv; o1[e] = lg[e + 4] * inv; }
        *(floatx4*)(g + (size_t)t * NE) = o0;
        *(floatx4*)(g + (size_t)t * NE + 4) = o1;
      }
    }
    __syncthreads();
    // write out half h in fragment-major order: 4 passes x 256 units of 16B
#pragma unroll
    for (int p = 0; p < 4; ++p) {
      const int u = p * 256 + tid;           // [0,1024)
      const int lr3 = u & 7;
      const int lq = (u >> 3) & 3;
      const int kkv = (u >> 5) & 1;
      const int kt = u >> 6;                 // [0,16)
      const bf16x8 v = *(const bf16x8*)(&xtile[lr3][kt * 64 + kkv * 32 + lq * 8]);
      const size_t off = (size_t)bg * 16384 +
          (size_t)((((kt * 2 + kkv) * 4 + lq) * 16) + h * 8 + lr3) * 8;
      *(bf16x8*)(xbf + off) = v;
    }
    __syncthreads();
  }
}

__global__ __launch_bounds__(256) void trans_kernel(
    const float* __restrict__ w, bf16* __restrict__ wt) {
  __shared__ __align__(16) float tile[64][65];
  const int b = blockIdx.x;
  const int e = b >> 8;
  const int i0 = ((b >> 4) & 15) * 64;
  const int o0 = (b & 15) * 64;
  const int tid = threadIdx.x;
  const int c4 = (tid & 15) * 4;
  const int r = tid >> 4;

  const float* src = w + ((size_t)e * DIN + i0) * DOUT + o0;
#pragma unroll
  for (int rr = r; rr < 64; rr += 16) {
    const floatx4 v = *(const floatx4*)(src + (size_t)rr * DOUT + c4);
    tile[rr][c4] = v[0]; tile[rr][c4 + 1] = v[1];
    tile[rr][c4 + 2] = v[2]; tile[rr][c4 + 3] = v[3];
  }
  __syncthreads();
  bf16* dst = wt + ((size_t)e * DOUT + o0) * DIN + i0;
#pragma unroll
  for (int rr = r; rr < 64; rr += 16) {
    union { bf16 b[4]; uint64_t u; } cv;
#pragma unroll
    for (int j = 0; j < 4; ++j) cv.b[j] = (bf16)tile[c4 + j][rr];
    *(uint64_t*)(dst + (size_t)rr * DIN + c4) = cv.u;
  }
}

// ---------------------------------------------------------------------------
// Fused MoE GEMM, R12: late-wait pipeline.
// R8 vs R11 post-mortem: both land at ~2530-2600 cyc/tile regardless of
// LDS/L2 mix => bound by the per-tile __syncthreads vmcnt(0) drain on loads
// issued ~300cyc earlier IN THE SAME body (T4 lesson: never wait on
// just-issued loads). R12 body: vmcnt(0) [covers stage(t), issued mid-body
// t-1, age ~1300cyc => usually retired] -> s_barrier [all waves' stage(t)
// landed; all reads(t-1) consumed] -> ds_read(t) -> issue stage(t+1) +
// A-frags(t+1) -> MFMA(t). Unroll x2 gives static A-register parity (no
// rotation => no mid-pipeline compiler waits). Known residual: fold g-loads
// force vmcnt(0) 8x total (~2us).
// A direct-to-register from fragment-major xbf (verified R11); B dbuf LDS
// with verified swizzle.
// ---------------------------------------------------------------------------
__global__ __launch_bounds__(256, 2) void moe_gemm(
    const bf16* __restrict__ xbf, const bf16* __restrict__ wt,
    const float* __restrict__ g, float* __restrict__ out) {
  __shared__ __align__(16) bf16 Bs[2][128 * 64];  // 2 x 16KB

  const int tid = threadIdx.x;
  // XCD swizzle (verified R7): per-XCD chunk = 16 bm x 4 bn.
  const int c = blockIdx.x & 7;
  const int jj = blockIdx.x >> 3;
  const int bm = (c >> 1) * 16 + (jj & 15);   // 0..63
  const int bn = (c & 1) * 4 + (jj >> 4);     // 0..7
  const int lane = tid & 63;
  const int wave = tid >> 6;
  const int wm = wave >> 1, wn = wave & 1;
  const int lr = lane & 15, lq = lane >> 4;

  // B staging (verified R8): srow 0..31 (+32/pass), swizzled col.
  const int srow = tid >> 3;
  const int scol = (((tid & 7) ^ (srow & 7)) << 3);
  const int kx = lr & 7;

  const bf16* const bgp = wt + (size_t)(bn * 128 + srow) * DIN + scol;
  const bf16* const abase = xbf + (size_t)(bm * 8 + wm * 4) * 16384 + lane * 8;

  const floatx4 fzero = {0.f, 0.f, 0.f, 0.f};
  floatx4 accF[4][4], accE[4][4];
#pragma unroll
  for (int im = 0; im < 4; ++im)
#pragma unroll
    for (int in = 0; in < 4; ++in) { accF[im][in] = fzero; accE[im][in] = fzero; }

  const int tok0 = bm * 128 + wm * 64;

  // avv[parity][kk][im]; parity statically indexed (rule #20).
  bf16x8 avv[2][2][4];

  // prologue: stage B(0) -> Bs[0]; A-frags(0) -> avv[0]
  {
    bf16* const blp = &Bs[0][tid * 8];
#pragma unroll
    for (int j = 0; j < 4; ++j)
      async16(bgp + (size_t)(32 * j) * DIN, blp + j * 2048);
#pragma unroll
    for (int kk = 0; kk < 2; ++kk)
#pragma unroll
      for (int im = 0; im < 4; ++im)
        avv[0][kk][im] = *(const bf16x8*)(abase + (size_t)im * 16384 + kk * 512);
  }

  for (int t = 0; t < 128; t += 2) {
    // ---------------- body EVEN (tile t, parity 0) ----------------
    {
      asm volatile("s_waitcnt vmcnt(0)" ::: "memory");  // stage(t)+avv[0] landed
      __builtin_amdgcn_s_barrier();                     // all waves ready
      asm volatile("" ::: "memory");
      const bf16* const Bb = &Bs[0][0];
      bf16x8 bv[2][4];
#pragma unroll
      for (int kk = 0; kk < 2; ++kk) {
        const int kg = ((kk * 4 + lq) ^ kx) << 3;
#pragma unroll
        for (int in = 0; in < 4; ++in)
          bv[kk][in] = *(const bf16x8*)(Bb + (wn * 64 + in * 16 + lr) * 64 + kg);
      }
      // issue tile t+1: stage B -> Bs[1], A-frags -> avv[1]  (t+1 <= 127 always)
      {
        const int t1 = t + 1;
        const int kt1 = t1 & 15;
#pragma unroll
        for (int kk = 0; kk < 2; ++kk)
#pragma unroll
          for (int im = 0; im < 4; ++im)
            avv[1][kk][im] = *(const bf16x8*)(abase + (size_t)im * 16384 +
                                              (kt1 * 2 + kk) * 512);
        const bf16* const bsrc = bgp + ((size_t)(t1 >> 4) << 20) + (size_t)kt1 * 64;
        bf16* const blp = &Bs[1][tid * 8];
#pragma unroll
        for (int j = 0; j < 4; ++j)
          async16(bsrc + (size_t)(32 * j) * DIN, blp + j * 2048);
      }
      __builtin_amdgcn_s_setprio(1);
#pragma unroll
      for (int kk = 0; kk < 2; ++kk)
#pragma unroll
        for (int im = 0; im < 4; ++im)
#pragma unroll
          for (int in = 0; in < 4; ++in)
            accE[im][in] = __builtin_amdgcn_mfma_f32_16x16x32_bf16(
                avv[0][kk][im], bv[kk][in], accE[im][in], 0, 0, 0);
      __builtin_amdgcn_s_setprio(0);
    }
    // ---------------- body ODD (tile t+1, parity 1) ----------------
    {
      asm volatile("s_waitcnt vmcnt(0)" ::: "memory");  // stage(t+1)+avv[1] landed
      __builtin_amdgcn_s_barrier();
      asm volatile("" ::: "memory");
      const bf16* const Bb = &Bs[1][0];
      bf16x8 bv[2][4];
#pragma unroll
      for (int kk = 0; kk < 2; ++kk) {
        const int kg = ((kk * 4 + lq) ^ kx) << 3;
#pragma unroll
        for (int in = 0; in < 4; ++in)
          bv[kk][in] = *(const bf16x8*)(Bb + (wn * 64 + in * 16 + lr) * 64 + kg);
      }
      // issue tile t+2: stage B -> Bs[0], A-frags -> avv[0]
      const int t2 = t + 2;
      if (t2 < 128) {
        const int kt2 = t2 & 15;
#pragma unroll
        for (int kk = 0; kk < 2; ++kk)
#pragma unroll
          for (int im = 0; im < 4; ++im)
            avv[0][kk][im] = *(const bf16x8*)(abase + (size_t)im * 16384 +
                                              (kt2 * 2 + kk) * 512);
        const bf16* const bsrc = bgp + ((size_t)(t2 >> 4) << 20) + (size_t)kt2 * 64;
        bf16* const blp = &Bs[0][tid * 8];
#pragma unroll
        for (int j = 0; j < 4; ++j)
          async16(bsrc + (size_t)(32 * j) * DIN, blp + j * 2048);
      }
      __builtin_amdgcn_s_setprio(1);
#pragma unroll
      for (int kk = 0; kk < 2; ++kk)
#pragma unroll
        for (int im = 0; im < 4; ++im)
#pragma unroll
          for (int in = 0; in < 4; ++in)
            accE[im][in] = __builtin_amdgcn_mfma_f32_16x16x32_bf16(
                avv[1][kk][im], bv[kk][in], accE[im][in], 0, 0, 0);
      __builtin_amdgcn_s_setprio(0);
    }
    // ---------------- expert boundary fold (t+1 = 15,31,...,127) ----------
    if (((t + 1) & 15) == 15) {
      const int e = (t + 1) >> 4;
#pragma unroll
      for (int im = 0; im < 4; ++im) {
        float gv[4];
#pragma unroll
        for (int r = 0; r < 4; ++r)
          gv[r] = g[(size_t)(tok0 + im * 16 + lq * 4 + r) * NE + e];
#pragma unroll
        for (int in = 0; in < 4; ++in)
#pragma unroll
          for (int r = 0; r < 4; ++r) {
            accF[im][in][r] += gv[r] * accE[im][in][r];
            accE[im][in][r] = 0.f;
          }
      }
    }
  }

#pragma unroll
  for (int im = 0; im < 4; ++im)
#pragma unroll
    for (int in = 0; in < 4; ++in) {
      const int col = bn * 128 + wn * 64 + in * 16 + lr;
#pragma unroll
      for (int r = 0; r < 4; ++r)
        out[(size_t)(tok0 + im * 16 + lq * 4 + r) * DOUT + col] =
            accF[im][in][r];
    }
}

// ---------------------------------------------------------------------------
extern "C" void kernel_launch(void* const* d_in, const int* in_sizes, int n_in,
                              void* d_out, int out_size, void* d_ws,
                              size_t ws_size, hipStream_t stream) {
  const float* x  = (const float*)d_in[0];
  const float* gw = (const float*)d_in[1];
  const float* gb = (const float*)d_in[2];
  const float* w  = (const float*)d_in[3];
  float* out = (float*)d_out;

  char* ws = (char*)d_ws;
  float* g   = (float*)ws;
  bf16* xbf  = (bf16*)(ws + 262144);
  bf16* wt   = (bf16*)(ws + 262144 + (size_t)TOKENS * DIN * 2);

  trans_kernel<<<2048, 256, 0, stream>>>(w, wt);
  gate_kernel<<<512, 256, 0, stream>>>(x, gw, gb, g, xbf);
  moe_gemm<<<512, 256, 0, stream>>>(xbf, wt, g, out);
}